// Round 1
// baseline (364.241 us; speedup 1.0000x reference)
//
#include <hip/hip_runtime.h>

#define NB 256      // batch
#define NC 512      // codebooks
#define NK 1024     // codes per book
#define NE 64       // embedding dim
#define KT 64       // k-tile

// One block per c. One thread per batch row b. Thread keeps mu[b, c*64..] in
// 64 VGPRs; dict tile staged in LDS, read via uniform-address broadcasts
// (always bank-conflict-free). d2 computed during staging via shuffles.
// one_hot zero-fill interleaved with compute so writes overlap VALU work.
__global__ __launch_bounds__(256, 2)
void vq_kernel(const float* __restrict__ mu,
               const float* __restrict__ dict,
               float* __restrict__ z,
               float* __restrict__ z_embed,
               float* __restrict__ one_hot)
{
    const int c   = blockIdx.x;
    const int tid = threadIdx.x;
    const int b   = tid;

    __shared__ __align__(16) float DT[KT * NE];   // [k][e] row-major, 16 KB
    __shared__ float d2t[KT];
    __shared__ int   bestk_sh[NB];

    // ---- mu row -> registers (64 floats), m2 sequential over e ----
    const float* murow = mu + (size_t)b * (NC * NE) + (size_t)c * NE;
    float4 m4[16];
#pragma unroll
    for (int i = 0; i < 16; ++i) m4[i] = ((const float4*)murow)[i];

    float m2 = 0.f;
#pragma unroll
    for (int i = 0; i < 16; ++i) {
        m2 = fmaf(m4[i].x, m4[i].x, m2);
        m2 = fmaf(m4[i].y, m4[i].y, m2);
        m2 = fmaf(m4[i].z, m4[i].z, m2);
        m2 = fmaf(m4[i].w, m4[i].w, m2);
    }

    float best  = 3.4e38f;
    int   bestk = 0;

    const int ch   = tid & 15;   // e-chunk (float4) within a dict row
    const int row0 = tid >> 4;   // 0..15

    const float4* dict4 = (const float4*)(dict + (size_t)c * NK * NE);

    // prefetch tile 0 (4 float4 per thread)
    float4 p0 = dict4[(size_t)(row0 +  0) * 16 + ch];
    float4 p1 = dict4[(size_t)(row0 + 16) * 16 + ch];
    float4 p2 = dict4[(size_t)(row0 + 32) * 16 + ch];
    float4 p3 = dict4[(size_t)(row0 + 48) * 16 + ch];

    for (int t = 0; t < NK / KT; ++t) {
        // ---- stage tile into LDS + d2 via shuffle over the 16 ch-lanes ----
#pragma unroll
        for (int i = 0; i < 4; ++i) {
            float4 pv = (i == 0) ? p0 : (i == 1) ? p1 : (i == 2) ? p2 : p3;
            int r = row0 + 16 * i;
            ((float4*)DT)[r * 16 + ch] = pv;
            float s = pv.x * pv.x;
            s = fmaf(pv.y, pv.y, s);
            s = fmaf(pv.z, pv.z, s);
            s = fmaf(pv.w, pv.w, s);
            s += __shfl_xor(s, 1, 64);
            s += __shfl_xor(s, 2, 64);
            s += __shfl_xor(s, 4, 64);
            s += __shfl_xor(s, 8, 64);
            if (ch == 0) d2t[r] = s;
        }
        __syncthreads();

        // ---- prefetch next tile (latency hides under compute below) ----
        if (t + 1 < NK / KT) {
            size_t base = (size_t)(t + 1) * KT;
            p0 = dict4[(base + row0 +  0) * 16 + ch];
            p1 = dict4[(base + row0 + 16) * 16 + ch];
            p2 = dict4[(base + row0 + 32) * 16 + ch];
            p3 = dict4[(base + row0 + 48) * 16 + ch];
        }

        // ---- 64 dots, 4 k at a time; uniform-address LDS broadcast reads ----
        for (int kk = 0; kk < KT; kk += 4) {
            const float4* r0 = (const float4*)(DT + (kk + 0) * NE);
            const float4* r1 = (const float4*)(DT + (kk + 1) * NE);
            const float4* r2 = (const float4*)(DT + (kk + 2) * NE);
            const float4* r3 = (const float4*)(DT + (kk + 3) * NE);
            float a0 = 0.f, a1 = 0.f, a2 = 0.f, a3 = 0.f;
#pragma unroll
            for (int e4 = 0; e4 < 16; ++e4) {
                float4 mm = m4[e4];
                float4 d0 = r0[e4], d1 = r1[e4], d2v = r2[e4], d3 = r3[e4];
                a0 = fmaf(mm.x, d0.x, a0);  a0 = fmaf(mm.y, d0.y, a0);
                a0 = fmaf(mm.z, d0.z, a0);  a0 = fmaf(mm.w, d0.w, a0);
                a1 = fmaf(mm.x, d1.x, a1);  a1 = fmaf(mm.y, d1.y, a1);
                a1 = fmaf(mm.z, d1.z, a1);  a1 = fmaf(mm.w, d1.w, a1);
                a2 = fmaf(mm.x, d2v.x, a2); a2 = fmaf(mm.y, d2v.y, a2);
                a2 = fmaf(mm.z, d2v.z, a2); a2 = fmaf(mm.w, d2v.w, a2);
                a3 = fmaf(mm.x, d3.x, a3);  a3 = fmaf(mm.y, d3.y, a3);
                a3 = fmaf(mm.z, d3.z, a3);  a3 = fmaf(mm.w, d3.w, a3);
            }
            // dist = (m2 - 2*dot) + d2  — same elementwise rounding as ref
            int kg = t * KT + kk;
            {
                float dist = (m2 - 2.f * a0) + d2t[kk + 0];
                bool u = dist < best; best = u ? dist : best; bestk = u ? (kg + 0) : bestk;
            }
            {
                float dist = (m2 - 2.f * a1) + d2t[kk + 1];
                bool u = dist < best; best = u ? dist : best; bestk = u ? (kg + 1) : bestk;
            }
            {
                float dist = (m2 - 2.f * a2) + d2t[kk + 2];
                bool u = dist < best; best = u ? dist : best; bestk = u ? (kg + 2) : bestk;
            }
            {
                float dist = (m2 - 2.f * a3) + d2t[kk + 3];
                bool u = dist < best; best = u ? dist : best; bestk = u ? (kg + 3) : bestk;
            }
        }

        // ---- zero-fill one_hot for this tile's k-range (overlaps compute) ----
        {
            const float4 zero4 = make_float4(0.f, 0.f, 0.f, 0.f);
            size_t kbase = (size_t)c * NK + (size_t)t * KT;   // in floats
#pragma unroll
            for (int ii = 0; ii < 16; ++ii) {
                int i  = tid + 256 * ii;        // 0..4095
                int bb = i >> 4;                // 0..255
                int cc = i & 15;                // float4 chunk within KT
                ((float4*)one_hot)[((size_t)bb * (NC * NK) + kbase) / 4 + cc] = zero4;
            }
        }
        __syncthreads();   // DT/d2t reusable; also orders one_hot zeros
    }

    bestk_sh[b] = bestk;
    __syncthreads();

    // ---- gather z / z_embed, coalesced (16 lanes cover one 256B row) ----
#pragma unroll
    for (int ii = 0; ii < 16; ++ii) {
        int i  = tid + 256 * ii;
        int bb = i >> 4;
        int cc = i & 15;
        float4 v = dict4[(size_t)bestk_sh[bb] * 16 + cc];
        size_t off = ((size_t)bb * (NC * NE) + (size_t)c * NE) / 4 + cc;
        ((float4*)z)[off]       = v;
        ((float4*)z_embed)[off] = v;
    }

    // ---- fixup the single 1.0 (zeros ordered before via barriers) ----
    one_hot[(size_t)b * (NC * NK) + (size_t)c * NK + bestk] = 1.0f;
}

extern "C" void kernel_launch(void* const* d_in, const int* in_sizes, int n_in,
                              void* d_out, int out_size, void* d_ws, size_t ws_size,
                              hipStream_t stream) {
    const float* mu   = (const float*)d_in[0];
    const float* dict = (const float*)d_in[1];
    float* z       = (float*)d_out;
    float* z_embed = (float*)d_out + (size_t)NB * NC * NE;
    float* one_hot = (float*)d_out + (size_t)2 * NB * NC * NE;
    vq_kernel<<<dim3(NC), dim3(256), 0, stream>>>(mu, dict, z, z_embed, one_hot);
}

// Round 3
// 345.828 us; speedup vs baseline: 1.0532x; 1.0532x over previous
//
#include <hip/hip_runtime.h>

#define NB 256      // batch
#define NC 512      // codebooks
#define NK 1024     // codes per book
#define NE 64       // embedding dim
#define KT 64       // k-tile
#define KHALF 512   // k range per half
#define TILES 8     // tiles per half

typedef float f32x4 __attribute__((ext_vector_type(4)));   // nontemporal-friendly

// One block per c. 512 threads = 256 batch rows x 2 k-halves. Each half
// stages its own dict tile into its own LDS buffer (uniform-address broadcast
// reads, conflict-free). In-block argmin combine at the end. one_hot zeros,
// z, z_embed written nontemporal (never re-read).
__global__ __launch_bounds__(512, 4)
void vq_kernel(const float* __restrict__ mu,
               const float* __restrict__ dict,
               float* __restrict__ z,
               float* __restrict__ z_embed,
               float* __restrict__ one_hot)
{
    const int c   = blockIdx.x;
    const int tid = threadIdx.x;
    const int b   = tid & 255;     // batch row
    const int h   = tid >> 8;      // k-half (0 or 1) — wave-aligned

    __shared__ __align__(16) float DT[2][KT * NE];   // 2 x 16 KB
    __shared__ float d2t[2][KT];
    __shared__ float bestd_sh[NB];
    __shared__ int   bestk_sh[NB];
    __shared__ int   finalk_sh[NB];

    // ---- mu row -> registers (64 floats), m2 sequential over e ----
    const float* murow = mu + (size_t)b * (NC * NE) + (size_t)c * NE;
    float4 m4[16];
#pragma unroll
    for (int i = 0; i < 16; ++i) m4[i] = ((const float4*)murow)[i];

    float m2 = 0.f;
#pragma unroll
    for (int i = 0; i < 16; ++i) {
        m2 = fmaf(m4[i].x, m4[i].x, m2);
        m2 = fmaf(m4[i].y, m4[i].y, m2);
        m2 = fmaf(m4[i].z, m4[i].z, m2);
        m2 = fmaf(m4[i].w, m4[i].w, m2);
    }

    float best  = 3.4e38f;
    int   bestk = 0;

    const int ch   = b & 15;       // float4 chunk within a dict row
    const int row0 = b >> 4;       // 0..15

    const float4* dict4 = (const float4*)(dict + (size_t)c * NK * NE);
    const size_t  hk    = (size_t)h * KHALF;   // this half's k offset

    // prefetch tile 0 of this half
    float4 p0 = dict4[(hk + row0 +  0) * 16 + ch];
    float4 p1 = dict4[(hk + row0 + 16) * 16 + ch];
    float4 p2 = dict4[(hk + row0 + 32) * 16 + ch];
    float4 p3 = dict4[(hk + row0 + 48) * 16 + ch];

    for (int t = 0; t < TILES; ++t) {
        // ---- stage tile into DT[h] + d2 via 16-lane shuffle reduce ----
        float* DTH = DT[h];
#pragma unroll
        for (int i = 0; i < 4; ++i) {
            float4 pv = (i == 0) ? p0 : (i == 1) ? p1 : (i == 2) ? p2 : p3;
            int r = row0 + 16 * i;
            ((float4*)DTH)[r * 16 + ch] = pv;
            float s = pv.x * pv.x;
            s = fmaf(pv.y, pv.y, s);
            s = fmaf(pv.z, pv.z, s);
            s = fmaf(pv.w, pv.w, s);
            s += __shfl_xor(s, 1, 64);
            s += __shfl_xor(s, 2, 64);
            s += __shfl_xor(s, 4, 64);
            s += __shfl_xor(s, 8, 64);
            if (ch == 0) d2t[h][r] = s;
        }
        __syncthreads();

        // ---- prefetch next tile ----
        if (t + 1 < TILES) {
            size_t base = hk + (size_t)(t + 1) * KT;
            p0 = dict4[(base + row0 +  0) * 16 + ch];
            p1 = dict4[(base + row0 + 16) * 16 + ch];
            p2 = dict4[(base + row0 + 32) * 16 + ch];
            p3 = dict4[(base + row0 + 48) * 16 + ch];
        }

        // ---- 64 dots, 4 k at a time; uniform-address LDS broadcasts ----
        for (int kk = 0; kk < KT; kk += 4) {
            const float4* r0 = (const float4*)(DTH + (kk + 0) * NE);
            const float4* r1 = (const float4*)(DTH + (kk + 1) * NE);
            const float4* r2 = (const float4*)(DTH + (kk + 2) * NE);
            const float4* r3 = (const float4*)(DTH + (kk + 3) * NE);
            float a0 = 0.f, a1 = 0.f, a2 = 0.f, a3 = 0.f;
#pragma unroll
            for (int e4 = 0; e4 < 16; ++e4) {
                float4 mm = m4[e4];
                float4 d0 = r0[e4], d1 = r1[e4], d2v = r2[e4], d3 = r3[e4];
                a0 = fmaf(mm.x, d0.x, a0);  a0 = fmaf(mm.y, d0.y, a0);
                a0 = fmaf(mm.z, d0.z, a0);  a0 = fmaf(mm.w, d0.w, a0);
                a1 = fmaf(mm.x, d1.x, a1);  a1 = fmaf(mm.y, d1.y, a1);
                a1 = fmaf(mm.z, d1.z, a1);  a1 = fmaf(mm.w, d1.w, a1);
                a2 = fmaf(mm.x, d2v.x, a2); a2 = fmaf(mm.y, d2v.y, a2);
                a2 = fmaf(mm.z, d2v.z, a2); a2 = fmaf(mm.w, d2v.w, a2);
                a3 = fmaf(mm.x, d3.x, a3);  a3 = fmaf(mm.y, d3.y, a3);
                a3 = fmaf(mm.z, d3.z, a3);  a3 = fmaf(mm.w, d3.w, a3);
            }
            // dist = (m2 - 2*dot) + d2 — same elementwise rounding as ref
            int kg = (int)hk + t * KT + kk;
            {
                float dist = (m2 - 2.f * a0) + d2t[h][kk + 0];
                bool u = dist < best; best = u ? dist : best; bestk = u ? (kg + 0) : bestk;
            }
            {
                float dist = (m2 - 2.f * a1) + d2t[h][kk + 1];
                bool u = dist < best; best = u ? dist : best; bestk = u ? (kg + 1) : bestk;
            }
            {
                float dist = (m2 - 2.f * a2) + d2t[h][kk + 2];
                bool u = dist < best; best = u ? dist : best; bestk = u ? (kg + 2) : bestk;
            }
            {
                float dist = (m2 - 2.f * a3) + d2t[h][kk + 3];
                bool u = dist < best; best = u ? dist : best; bestk = u ? (kg + 3) : bestk;
            }
        }

        // ---- zero-fill one_hot for this half's tile k-range (overlaps) ----
        {
            const f32x4 zero4 = (f32x4)(0.f);
            size_t kbase = (size_t)c * NK + hk + (size_t)t * KT;   // float idx
#pragma unroll
            for (int ii = 0; ii < 16; ++ii) {
                int i  = b + 256 * ii;          // 0..4095 within this half
                int bb = i >> 4;                // 0..255
                int cc = i & 15;                // float4 chunk within KT
                __builtin_nontemporal_store(
                    zero4,
                    &((f32x4*)one_hot)[((size_t)bb * (NC * NK) + kbase) / 4 + cc]);
            }
        }
        __syncthreads();   // DT/d2t reusable; also orders one_hot zeros
    }

    // ---- combine the two k-halves (upper half has larger indices: strict <) ----
    if (h == 1) { bestd_sh[b] = best; bestk_sh[b] = bestk; }
    __syncthreads();       // also drains all zero stores (vmcnt(0))
    if (h == 0) {
        float d1 = bestd_sh[b];
        int   k1 = bestk_sh[b];
        int   fk = (d1 < best) ? k1 : bestk;
        finalk_sh[b] = fk;
        // fixup the single 1.0 (zeros drained by the barrier above)
        one_hot[(size_t)b * (NC * NK) + (size_t)c * NK + fk] = 1.0f;
    }
    __syncthreads();

    // ---- gather z / z_embed, coalesced (16 lanes cover one 256B row) ----
#pragma unroll
    for (int ii = 0; ii < 8; ++ii) {
        int i  = tid + 512 * ii;    // 0..4095
        int bb = i >> 4;
        int cc = i & 15;
        float4 vv = dict4[(size_t)finalk_sh[bb] * 16 + cc];
        f32x4 v;  v.x = vv.x; v.y = vv.y; v.z = vv.z; v.w = vv.w;
        size_t off = ((size_t)bb * (NC * NE) + (size_t)c * NE) / 4 + cc;
        __builtin_nontemporal_store(v, &((f32x4*)z)[off]);
        __builtin_nontemporal_store(v, &((f32x4*)z_embed)[off]);
    }
}

extern "C" void kernel_launch(void* const* d_in, const int* in_sizes, int n_in,
                              void* d_out, int out_size, void* d_ws, size_t ws_size,
                              hipStream_t stream) {
    const float* mu   = (const float*)d_in[0];
    const float* dict = (const float*)d_in[1];
    float* z       = (float*)d_out;
    float* z_embed = (float*)d_out + (size_t)NB * NC * NE;
    float* one_hot = (float*)d_out + (size_t)2 * NB * NC * NE;
    vq_kernel<<<dim3(NC), dim3(512), 0, stream>>>(mu, dict, z, z_embed, one_hot);
}